// Round 1
// baseline (38020.731 us; speedup 1.0000x reference)
//
#include <hip/hip_runtime.h>
#include <stdint.h>

#define H4T 2048
#define BATCHN 32
#define TSTEPS 1000
#define NBLK 256
#define NTHR 512
#define NSLICE 16   // i-slices == jl groups (NTHR = 32 * NSLICE)

// ws layout:
//   [0, 4096)                : per-step barrier counters (TSTEPS * u32 = 4000 B)
//   [4096, 4096+262144)      : h buffer 0  (interleaved [i/4][b][4] floats)
//   [4096+262144, +262144)   : h buffer 1

__device__ __forceinline__ float ht_clip(float w) {
  return fminf(fmaxf(w, 1e-15f), 1.0f);
}

// W_rec[j, i] for j = g*512 + jj. Block-sparse per reference.
__device__ float wval(int g, int jj, int i,
                      const float* s2s_f, const float* t2s, const float* a2s,
                      const float* s2n, const float* n2t,
                      const float* t2a, const float* a2a) {
  int ig = i >> 9;
  int ii = i & 511;
  float v = 0.0f;
  if (g == 0) {
    if (ig == 0)      v = -s2s_f[jj * 512 + ii];                                  // -(str2str_fixed)
    else if (ig == 2) v = (jj >= 256) ? ht_clip(t2s[jj * 512 + ii]) : 0.0f;       // thal2str row-masked
    else if (ig == 3) v = (ii < 359) ? ht_clip(a2s[jj * 512 + ii]) : 0.0f;        // alm2str col-masked
  } else if (g == 1) {
    if (ig == 0)      v = -ht_clip(s2n[jj * 512 + ii]);                           // -str2snr
  } else if (g == 2) {
    if (ig == 1)      v = -ht_clip(n2t[jj * 512 + ii]);                           // -snr2thal
  } else {
    if (ig == 2)      v = ht_clip(t2a[jj * 512 + ii]);                            // thal2alm
    else if (ig == 3) v = ht_clip(a2a[jj * 512 + ii]) * ((ii < 359) ? 1.0f : -1.0f); // alm2alm * d_alm
  }
  return v;
}

template<int NCOLS, int IEXT, bool SPLIT, int LOG2NC>
__device__ __forceinline__ void run_group(
    int g, int j0, int ibase4, float tonicv,
    const float* __restrict__ inp, const float* __restrict__ inhib,
    const float* s2s_f, const float* t2s, const float* a2s,
    const float* s2n, const float* n2t, const float* t2a, const float* a2a,
    const float* __restrict__ inpw,
    float* __restrict__ out_hn, float* __restrict__ out_rnn,
    float* hbuf0, float* hbuf1, unsigned int* cnt,
    float* Wl, float* red, float* outb, float* iwl)
{
  const int tid = threadIdx.x;
  const int b   = tid & 31;     // batch lane
  const int jl  = tid >> 5;     // i-slice id (0..15)
  constexpr int IEXT4  = IEXT / 4;
  constexpr int SLICE4 = IEXT4 / NSLICE;

  // ---- one-time: build this block's W slice in LDS (cols j0..j0+NCOLS-1) ----
  for (int idx = tid; idx < NCOLS * IEXT; idx += NTHR) {
    int c  = idx / IEXT;
    int fi = idx - c * IEXT;
    int i;
    if (SPLIT) i = (fi < 512) ? fi : (fi + 512);   // g0: [0,512) U [1024,2048)
    else       i = ibase4 * 4 + fi;
    Wl[c * IEXT + fi] = wval(g, (j0 + c) & 511, i, s2s_f, t2s, a2s, s2n, n2t, t2a, a2a);
  }
  if (tid < NCOLS) {
    int j = j0 + tid;
    iwl[tid] = (j >= 256 && j < 512) ? ht_clip(inpw[j]) : 0.0f;  // strthal-masked input proj
  }
  __syncthreads();

  const float dtc = 0.01f;
  int cur = 0;
  const float4* __restrict__ Wl4 = (const float4*)Wl;

  for (int t = 0; t < TSTEPS; ++t) {
    const float* hb  = cur ? hbuf1 : hbuf0;
    float*       hbn = cur ? hbuf0 : hbuf1;
    const float4* __restrict__ hb4 = (const float4*)hb;

    // ---- i-loop: partial dot products over this thread's i-slice ----
    float acc[NCOLS];
#pragma unroll
    for (int c = 0; c < NCOLS; ++c) acc[c] = 0.0f;

    for (int it = 0; it < SLICE4; ++it) {
      int fi4 = jl * SLICE4 + it;
      int i4  = ibase4 + (SPLIT ? ((fi4 >= 128) ? fi4 + 128 : fi4) : fi4);
      float4 hv = hb4[i4 * 32 + b];
#pragma unroll
      for (int c = 0; c < NCOLS; ++c) {
        float4 wv = Wl4[c * IEXT4 + fi4];
        acc[c] = fmaf(hv.x, wv.x, acc[c]);
        acc[c] = fmaf(hv.y, wv.y, acc[c]);
        acc[c] = fmaf(hv.z, wv.z, acc[c]);
        acc[c] = fmaf(hv.w, wv.w, acc[c]);
      }
    }

    // ---- write partials (conflict-free: lanes consecutive over b) ----
#pragma unroll
    for (int c = 0; c < NCOLS; ++c)
      red[(c * NSLICE + jl) * 33 + b] = acc[c];
    __syncthreads();

    // ---- reduce across slices + pointwise update ----
    if (tid < 32 * NCOLS) {
      int pb = tid & 31;
      int c  = tid >> 5;
      float s = 0.0f;
#pragma unroll
      for (int sl = 0; sl < NSLICE; ++sl)
        s += red[(c * NSLICE + sl) * 33 + pb];
      int j = j0 + c;
      float hold = hb[(j >> 2) * 128 + (pb << 2) + (j & 3)];
      float inh  = inhib[(size_t)pb * (TSTEPS * H4T) + (size_t)t * H4T + j];
      float iv   = inp[pb * TSTEPS + t];
      float d    = inh + tonicv + iv * iwl[c];
      float hnew = fmaxf(0.0f, fmaf(dtc, s + d - hold, hold));
      hbn[(j >> 2) * 128 + (pb << 2) + (j & 3)] = hnew;
      outb[pb * (NCOLS + 1) + c] = hnew;
    }
    __syncthreads();

    // ---- coalesced global store of rnn_out (and hn_last on final step) ----
    if (tid < 32 * NCOLS) {
      int c  = tid & (NCOLS - 1);
      int bb = tid >> LOG2NC;
      float v = outb[bb * (NCOLS + 1) + c];
      out_rnn[(size_t)bb * (TSTEPS * H4T) + (size_t)t * H4T + (j0 + c)] = v;
      if (t == TSTEPS - 1) out_hn[bb * H4T + (j0 + c)] = v;
    }

    // ---- device-wide barrier: per-step counter, release/acquire at agent scope ----
    __syncthreads();
    if (tid == 0) {
      __hip_atomic_fetch_add(&cnt[t], 1u, __ATOMIC_RELEASE, __HIP_MEMORY_SCOPE_AGENT);
      while (__hip_atomic_load(&cnt[t], __ATOMIC_RELAXED, __HIP_MEMORY_SCOPE_AGENT) < NBLK)
        __builtin_amdgcn_s_sleep(2);
    }
    __syncthreads();
    __builtin_amdgcn_fence(__ATOMIC_ACQUIRE, "agent");
    cur ^= 1;
  }
}

__global__ void prep_h0(const float* __restrict__ hn, float* __restrict__ hbuf0) {
  int e = blockIdx.x * blockDim.x + threadIdx.x;
  if (e < BATCHN * H4T) {
    int b = e >> 11;
    int j = e & 2047;
    hbuf0[(j >> 2) * 128 + (b << 2) + (j & 3)] = hn[e];
  }
}

__global__ __launch_bounds__(NTHR) void rnn_persistent(
    const float* __restrict__ inp, const float* __restrict__ inhib,
    const float* s2s_f, const float* t2s, const float* a2s,
    const float* s2n, const float* n2t, const float* t2a, const float* a2a,
    const float* __restrict__ inpw,
    float* __restrict__ out_hn, float* __restrict__ out_rnn,
    float* hbuf0, float* hbuf1, unsigned int* cnt)
{
  __shared__ __align__(16) float Wl[8192];    // W slice, persistent across steps
  __shared__ float red[8448];                 // [NCOLS][NSLICE][33] partials
  __shared__ float outb[544];                 // [32][NCOLS+1] staged outputs
  __shared__ float iwl[16];

  int bid = blockIdx.x;
  if (bid < 128) {
    run_group<4, 1536, true, 2>(0, bid * 4, 0, 0.0f,
        inp, inhib, s2s_f, t2s, a2s, s2n, n2t, t2a, a2a, inpw,
        out_hn, out_rnn, hbuf0, hbuf1, cnt, Wl, red, outb, iwl);
  } else if (bid < 160) {
    run_group<16, 512, false, 4>(1, 512 + (bid - 128) * 16, 0, 0.7f,
        inp, inhib, s2s_f, t2s, a2s, s2n, n2t, t2a, a2a, inpw,
        out_hn, out_rnn, hbuf0, hbuf1, cnt, Wl, red, outb, iwl);
  } else if (bid < 192) {
    run_group<16, 512, false, 4>(2, 1024 + (bid - 160) * 16, 128, 1.0f,
        inp, inhib, s2s_f, t2s, a2s, s2n, n2t, t2a, a2a, inpw,
        out_hn, out_rnn, hbuf0, hbuf1, cnt, Wl, red, outb, iwl);
  } else {
    run_group<8, 1024, false, 3>(3, 1536 + (bid - 192) * 8, 256, 0.0f,
        inp, inhib, s2s_f, t2s, a2s, s2n, n2t, t2a, a2a, inpw,
        out_hn, out_rnn, hbuf0, hbuf1, cnt, Wl, red, outb, iwl);
  }
}

extern "C" void kernel_launch(void* const* d_in, const int* in_sizes, int n_in,
                              void* d_out, int out_size, void* d_ws, size_t ws_size,
                              hipStream_t stream) {
  const float* inp   = (const float*)d_in[0];   // [32,1000,1]
  const float* hn    = (const float*)d_in[1];   // [1,32,2048]
  const float* inhib = (const float*)d_in[2];   // [32,1000,2048]
  // d_in[3] = str2str_w (multiplied by 0.0 in reference -> unused)
  const float* t2a   = (const float*)d_in[4];   // thal2alm_w
  const float* t2s   = (const float*)d_in[5];   // thal2str_w
  const float* a2a   = (const float*)d_in[6];   // alm2alm_w
  const float* a2s   = (const float*)d_in[7];   // alm2str_w
  const float* s2n   = (const float*)d_in[8];   // str2snr_w
  const float* n2t   = (const float*)d_in[9];   // snr2thal_w
  const float* inpw  = (const float*)d_in[10];  // inp_weight [1,2048]
  const float* s2s_f = (const float*)d_in[11];  // str2str_fixed

  float* out_hn  = (float*)d_out;               // [1,32,2048]
  float* out_rnn = out_hn + BATCHN * H4T;       // [32,1000,2048]

  unsigned int* cnt = (unsigned int*)d_ws;
  float* hbuf0 = (float*)((char*)d_ws + 4096);
  float* hbuf1 = hbuf0 + BATCHN * H4T;

  hipMemsetAsync(d_ws, 0, 4096, stream);                 // zero barrier counters
  prep_h0<<<256, 256, 0, stream>>>(hn, hbuf0);           // h0 -> interleaved layout
  rnn_persistent<<<NBLK, NTHR, 0, stream>>>(
      inp, inhib, s2s_f, t2s, a2s, s2n, n2t, t2a, a2a, inpw,
      out_hn, out_rnn, hbuf0, hbuf1, cnt);
}

// Round 2
// 7102.993 us; speedup vs baseline: 5.3528x; 5.3528x over previous
//
#include <hip/hip_runtime.h>
#include <stdint.h>

#define H4T 2048
#define BATCHN 32
#define TSTEPS 1000
#define NBLK 256
#define NTHR 512
#define NSLICE 16   // i-slices == jl groups (NTHR = 32 * NSLICE)
#define WSTRIDE 8192

// ws layout:
//   [0, 256K)        : h buffer 0  (interleaved [i/4][b][4] floats)
//   [256K, 512K)     : h buffer 1
//   [512K, 512K+8M)  : packed W slices, 256 blocks x 8192 floats
//   [+8M, +16K)      : packed masked input weights, 256 x 16 floats

__device__ __forceinline__ float ht_clip(float w) {
  return fminf(fmaxf(w, 1e-15f), 1.0f);
}

// W_rec[j, i] for j = g*512 + jj. Block-sparse per reference.
__device__ float wval(int g, int jj, int i,
                      const float* s2s_f, const float* t2s, const float* a2s,
                      const float* s2n, const float* n2t,
                      const float* t2a, const float* a2a) {
  int ig = i >> 9;
  int ii = i & 511;
  float v = 0.0f;
  if (g == 0) {
    if (ig == 0)      v = -s2s_f[jj * 512 + ii];                                  // -(str2str_fixed)
    else if (ig == 2) v = (jj >= 256) ? ht_clip(t2s[jj * 512 + ii]) : 0.0f;       // thal2str row-masked
    else if (ig == 3) v = (ii < 359) ? ht_clip(a2s[jj * 512 + ii]) : 0.0f;        // alm2str col-masked
  } else if (g == 1) {
    if (ig == 0)      v = -ht_clip(s2n[jj * 512 + ii]);                           // -str2snr
  } else if (g == 2) {
    if (ig == 1)      v = -ht_clip(n2t[jj * 512 + ii]);                           // -snr2thal
  } else {
    if (ig == 2)      v = ht_clip(t2a[jj * 512 + ii]);                            // thal2alm
    else if (ig == 3) v = ht_clip(a2a[jj * 512 + ii]) * ((ii < 359) ? 1.0f : -1.0f); // alm2alm * d_alm
  }
  return v;
}

__global__ void prep_h0(const float* __restrict__ hn, float* __restrict__ hbuf0) {
  int e = blockIdx.x * blockDim.x + threadIdx.x;
  if (e < BATCHN * H4T) {
    int b = e >> 11;
    int j = e & 2047;
    hbuf0[(j >> 2) * 128 + (b << 2) + (j & 3)] = hn[e];
  }
}

// One-time per call: pack this problem's block-sparse W into per-block slabs.
__global__ __launch_bounds__(NTHR) void pack_w(
    const float* s2s_f, const float* t2s, const float* a2s,
    const float* s2n, const float* n2t, const float* t2a, const float* a2a,
    const float* __restrict__ inpw,
    float* __restrict__ wp, float* __restrict__ iwp)
{
  int bid = blockIdx.x, tid = threadIdx.x;
  int g, j0, NC, IE, ib4;
  if (bid < 128)      { g = 0; j0 = bid * 4;              NC = 4;  IE = 1536; ib4 = 0;   }
  else if (bid < 160) { g = 1; j0 = 512 + (bid - 128)*16; NC = 16; IE = 512;  ib4 = 0;   }
  else if (bid < 192) { g = 2; j0 = 1024 + (bid - 160)*16;NC = 16; IE = 512;  ib4 = 128; }
  else                { g = 3; j0 = 1536 + (bid - 192)*8; NC = 8;  IE = 1024; ib4 = 256; }

  for (int idx = tid; idx < NC * IE; idx += NTHR) {
    int c  = idx / IE;
    int fi = idx - c * IE;
    int i  = (g == 0) ? ((fi < 512) ? fi : fi + 512) : ib4 * 4 + fi;
    wp[(size_t)bid * WSTRIDE + idx] =
        wval(g, (j0 + c) & 511, i, s2s_f, t2s, a2s, s2n, n2t, t2a, a2a);
  }
  if (tid < NC) {
    int j = j0 + tid;
    iwp[bid * 16 + tid] = (j >= 256 && j < 512) ? ht_clip(inpw[j]) : 0.0f;
  }
}

template<int NCOLS, int IEXT, bool SPLIT, int LOG2NC>
__device__ __forceinline__ void step_group(
    int j0, int ibase4, float tonicv, int t,
    const float* __restrict__ inp, const float* __restrict__ inhib,
    const float* __restrict__ wp_blk, const float* __restrict__ iwp_blk,
    float* __restrict__ out_hn, float* __restrict__ out_rnn,
    const float* __restrict__ hb, float* __restrict__ hbn,
    float* Wl, float* red, float* outb, float* iwl)
{
  const int tid = threadIdx.x;
  const int b   = tid & 31;     // batch lane
  const int jl  = tid >> 5;     // i-slice id (0..15)
  constexpr int IEXT4  = IEXT / 4;
  constexpr int SLICE4 = IEXT4 / NSLICE;

  // ---- stage this block's packed W slab into LDS (pure float4 copy) ----
  {
    const float4* __restrict__ wsrc = (const float4*)wp_blk;
    float4* Wl4w = (float4*)Wl;
    for (int k = tid; k < NCOLS * IEXT4; k += NTHR) Wl4w[k] = wsrc[k];
  }
  if (tid < NCOLS) iwl[tid] = iwp_blk[tid];
  __syncthreads();

  const float dtc = 0.01f;
  const float4* __restrict__ hb4 = (const float4*)hb;
  const float4* __restrict__ Wl4 = (const float4*)Wl;

  // ---- i-loop: partial dot products over this thread's i-slice ----
  float acc[NCOLS];
#pragma unroll
  for (int c = 0; c < NCOLS; ++c) acc[c] = 0.0f;

  for (int it = 0; it < SLICE4; ++it) {
    int fi4 = jl * SLICE4 + it;
    int i4  = ibase4 + (SPLIT ? ((fi4 >= 128) ? fi4 + 128 : fi4) : fi4);
    float4 hv = hb4[i4 * 32 + b];
#pragma unroll
    for (int c = 0; c < NCOLS; ++c) {
      float4 wv = Wl4[c * IEXT4 + fi4];
      acc[c] = fmaf(hv.x, wv.x, acc[c]);
      acc[c] = fmaf(hv.y, wv.y, acc[c]);
      acc[c] = fmaf(hv.z, wv.z, acc[c]);
      acc[c] = fmaf(hv.w, wv.w, acc[c]);
    }
  }

  // ---- write partials (conflict-free: lanes consecutive over b) ----
#pragma unroll
  for (int c = 0; c < NCOLS; ++c)
    red[(c * NSLICE + jl) * 33 + b] = acc[c];
  __syncthreads();

  // ---- reduce across slices + pointwise update ----
  if (tid < 32 * NCOLS) {
    int pb = tid & 31;
    int c  = tid >> 5;
    float s = 0.0f;
#pragma unroll
    for (int sl = 0; sl < NSLICE; ++sl)
      s += red[(c * NSLICE + sl) * 33 + pb];
    int j = j0 + c;
    float hold = hb[(j >> 2) * 128 + (pb << 2) + (j & 3)];
    float inh  = inhib[(size_t)pb * (TSTEPS * H4T) + (size_t)t * H4T + j];
    float iv   = inp[pb * TSTEPS + t];
    float d    = inh + tonicv + iv * iwl[c];
    float hnew = fmaxf(0.0f, fmaf(dtc, s + d - hold, hold));
    hbn[(j >> 2) * 128 + (pb << 2) + (j & 3)] = hnew;
    outb[pb * (NCOLS + 1) + c] = hnew;
  }
  __syncthreads();

  // ---- coalesced global store of rnn_out (and hn_last on final step) ----
  if (tid < 32 * NCOLS) {
    int c  = tid & (NCOLS - 1);
    int bb = tid >> LOG2NC;
    float v = outb[bb * (NCOLS + 1) + c];
    out_rnn[(size_t)bb * (TSTEPS * H4T) + (size_t)t * H4T + (j0 + c)] = v;
    if (t == TSTEPS - 1) out_hn[bb * H4T + (j0 + c)] = v;
  }
}

__global__ __launch_bounds__(NTHR) void rnn_step(
    int t,
    const float* __restrict__ inp, const float* __restrict__ inhib,
    const float* __restrict__ wp, const float* __restrict__ iwp,
    float* __restrict__ out_hn, float* __restrict__ out_rnn,
    const float* __restrict__ hb, float* __restrict__ hbn)
{
  __shared__ __align__(16) float Wl[8192];    // W slice for this step
  __shared__ float red[8448];                 // [NCOLS][NSLICE][33] partials
  __shared__ float outb[544];                 // [32][NCOLS+1] staged outputs
  __shared__ float iwl[16];

  int bid = blockIdx.x;
  const float* wb = wp + (size_t)bid * WSTRIDE;
  const float* ib = iwp + bid * 16;

  if (bid < 128) {
    step_group<4, 1536, true, 2>(bid * 4, 0, 0.0f, t,
        inp, inhib, wb, ib, out_hn, out_rnn, hb, hbn, Wl, red, outb, iwl);
  } else if (bid < 160) {
    step_group<16, 512, false, 4>(512 + (bid - 128) * 16, 0, 0.7f, t,
        inp, inhib, wb, ib, out_hn, out_rnn, hb, hbn, Wl, red, outb, iwl);
  } else if (bid < 192) {
    step_group<16, 512, false, 4>(1024 + (bid - 160) * 16, 128, 1.0f, t,
        inp, inhib, wb, ib, out_hn, out_rnn, hb, hbn, Wl, red, outb, iwl);
  } else {
    step_group<8, 1024, false, 3>(1536 + (bid - 192) * 8, 256, 0.0f, t,
        inp, inhib, wb, ib, out_hn, out_rnn, hb, hbn, Wl, red, outb, iwl);
  }
}

extern "C" void kernel_launch(void* const* d_in, const int* in_sizes, int n_in,
                              void* d_out, int out_size, void* d_ws, size_t ws_size,
                              hipStream_t stream) {
  const float* inp   = (const float*)d_in[0];   // [32,1000,1]
  const float* hn    = (const float*)d_in[1];   // [1,32,2048]
  const float* inhib = (const float*)d_in[2];   // [32,1000,2048]
  // d_in[3] = str2str_w (multiplied by 0.0 in reference -> unused)
  const float* t2a   = (const float*)d_in[4];   // thal2alm_w
  const float* t2s   = (const float*)d_in[5];   // thal2str_w
  const float* a2a   = (const float*)d_in[6];   // alm2alm_w
  const float* a2s   = (const float*)d_in[7];   // alm2str_w
  const float* s2n   = (const float*)d_in[8];   // str2snr_w
  const float* n2t   = (const float*)d_in[9];   // snr2thal_w
  const float* inpw  = (const float*)d_in[10];  // inp_weight [1,2048]
  const float* s2s_f = (const float*)d_in[11];  // str2str_fixed

  float* out_hn  = (float*)d_out;               // [1,32,2048]
  float* out_rnn = out_hn + BATCHN * H4T;       // [32,1000,2048]

  float* hbuf0 = (float*)d_ws;
  float* hbuf1 = hbuf0 + BATCHN * H4T;
  float* wp    = hbuf1 + BATCHN * H4T;
  float* iwp   = wp + (size_t)NBLK * WSTRIDE;

  prep_h0<<<256, 256, 0, stream>>>(hn, hbuf0);
  pack_w<<<NBLK, NTHR, 0, stream>>>(s2s_f, t2s, a2s, s2n, n2t, t2a, a2a, inpw, wp, iwp);

  for (int t = 0; t < TSTEPS; ++t) {
    const float* hb  = (t & 1) ? hbuf1 : hbuf0;
    float*       hbn = (t & 1) ? hbuf0 : hbuf1;
    rnn_step<<<NBLK, NTHR, 0, stream>>>(t, inp, inhib, wp, iwp,
                                        out_hn, out_rnn, hb, hbn);
  }
}